// Round 4
// baseline (785.682 us; speedup 1.0000x reference)
//
#include <hip/hip_runtime.h>
#include <hip/hip_cooperative_groups.h>

namespace cg = cooperative_groups;

#define EPS 0.001f
#define HW_POS 1024          // 32*32 spatial positions per image
#define NCH 256              // channels
#define NCG 64               // channel groups of 4 (float4)
#define NB 256               // batch
#define NP 4                 // partitions
#define SPLIT 4              // blocks per image
#define POS_PER_BLOCK (HW_POS / SPLIT)   // 256 positions per block
#define N_PER_PC 65536.0f    // PS * HW_POS elements per (partition, channel)
#define NBLK (NB * SPLIT)    // 1024 blocks — fully co-resident (4 blocks/CU)

typedef float f32x4 __attribute__((ext_vector_type(4)));

// Single fused cooperative kernel:
//   phase 0: block 0 zeroes the 8 KB accumulator (asum|asq)
//   grid.sync()
//   phase 1: per-(partition,channel) sums (LDS reduce + atomics)  [= k_partial]
//   grid.sync()
//   phase 2: per-thread fused affine coeffs from raw sums          [= k_finalize]
//   phase 3: normalize own slice in REVERSE with nt load/store     [= k_norm]
// Co-residency (1024 blocks, 4/CU, 16 waves/CU) is guaranteed by
// __launch_bounds__(256,4): VGPR capped at 128, LDS 8 KB/block.
// Because all blocks finish phase 1 near-simultaneously, each block's own
// slice tail is its most-recently-touched data -> reversing the OWN slice
// maximizes L2/L3 hits in phase 3 (better than a global reverse).
__global__ __launch_bounds__(256, 4)
void k_fused(const float4* __restrict__ x,
             const float*  __restrict__ gamma,
             const float*  __restrict__ beta,
             const int*    __restrict__ perm,
             float4*       __restrict__ out,
             float*        __restrict__ asum,
             float*        __restrict__ asq) {
    cg::grid_group grid = cg::this_grid();

    const int blk   = (int)blockIdx.x;
    const int j     = blk >> 2;          // shuffled image index
    const int chunk = blk & (SPLIT - 1);
    const int b     = perm[j];
    const int p     = j >> 6;            // partition
    const int t     = (int)threadIdx.x;
    const int cgp   = t & 63;            // float4 channel group
    const int srow  = t >> 6;            // spatial phase (wave id)

    // ---- phase 0: zero accumulators (asum|asq contiguous, 2048 floats) ----
    if (blk == 0) {
        #pragma unroll
        for (int k = 0; k < 8; ++k) asum[k * 256 + t] = 0.f;
    }
    grid.sync();

    // ---- phase 1: partial sums over this block's 256 positions ----
    const float4* xb = x + (size_t)b * (HW_POS * NCG);
    const int s0 = chunk * POS_PER_BLOCK;

    float4 s = make_float4(0.f, 0.f, 0.f, 0.f);
    float4 q = make_float4(0.f, 0.f, 0.f, 0.f);
    #pragma unroll 8
    for (int si = s0 + srow; si < s0 + POS_PER_BLOCK; si += 4) {
        float4 v = xb[(size_t)si * NCG + cgp];
        s.x += v.x; s.y += v.y; s.z += v.z; s.w += v.w;
        q.x += v.x * v.x; q.y += v.y * v.y; q.z += v.z * v.z; q.w += v.w * v.w;
    }

    __shared__ float4 ls[4][64];
    __shared__ float4 lq[4][64];
    ls[srow][cgp] = s;
    lq[srow][cgp] = q;
    __syncthreads();

    if (srow == 0) {
        float4 a0 = ls[0][cgp], a1 = ls[1][cgp], a2 = ls[2][cgp], a3 = ls[3][cgp];
        float4 b0 = lq[0][cgp], b1 = lq[1][cgp], b2 = lq[2][cgp], b3 = lq[3][cgp];
        float ts[4] = { a0.x + a1.x + a2.x + a3.x,
                        a0.y + a1.y + a2.y + a3.y,
                        a0.z + a1.z + a2.z + a3.z,
                        a0.w + a1.w + a2.w + a3.w };
        float tq[4] = { b0.x + b1.x + b2.x + b3.x,
                        b0.y + b1.y + b2.y + b3.y,
                        b0.z + b1.z + b2.z + b3.z,
                        b0.w + b1.w + b2.w + b3.w };
        float* sp = asum + p * NCH + cgp * 4;
        float* qp = asq  + p * NCH + cgp * 4;
        #pragma unroll
        for (int k = 0; k < 4; ++k) {
            atomicAdd(sp + k, ts[k]);
            atomicAdd(qp + k, tq[k]);
        }
    }

    __threadfence();     // make atomics visible before the grid-wide acquire
    grid.sync();

    // ---- phase 2: fused affine coefficients for this thread's 4 channels ----
    float4 sc, sh;
    {
        float scv[4], shv[4];
        #pragma unroll
        for (int k = 0; k < 4; ++k) {
            const int c    = cgp * 4 + k;
            const float sv = asum[p * NCH + c];
            const float qv = asq [p * NCH + c];
            const float mean = sv * (1.0f / N_PER_PC);
            const float var  = qv * (1.0f / N_PER_PC) - mean * mean;
            const float inv  = rsqrtf(var + EPS);
            const float g    = gamma[p * NCH + c];
            scv[k] = g * inv;
            shv[k] = beta[p * NCH + c] - mean * scv[k];
        }
        sc = make_float4(scv[0], scv[1], scv[2], scv[3]);
        sh = make_float4(shv[0], shv[1], shv[2], shv[3]);
    }

    // ---- phase 3: normalize OWN slice in reverse (LIFO -> L2/L3 hits) ----
    float4* ob = out + (size_t)b * (HW_POS * NCG);
    #pragma unroll 8
    for (int si = s0 + POS_PER_BLOCK - 4 + srow; si >= s0; si -= 4) {
        const size_t idx = (size_t)si * NCG + cgp;
        f32x4 v = __builtin_nontemporal_load((const f32x4*)(xb + idx));
        f32x4 r;
        r.x = v.x * sc.x + sh.x;
        r.y = v.y * sc.y + sh.y;
        r.z = v.z * sc.z + sh.z;
        r.w = v.w * sc.w + sh.w;
        __builtin_nontemporal_store(r, (f32x4*)(ob + idx));
    }
}

extern "C" void kernel_launch(void* const* d_in, const int* in_sizes, int n_in,
                              void* d_out, int out_size, void* d_ws, size_t ws_size,
                              hipStream_t stream) {
    const float4* x     = (const float4*)d_in[0];
    const float*  gamma = (const float*)d_in[1];
    const float*  beta  = (const float*)d_in[2];
    const int*    perm  = (const int*)d_in[3];
    float4* out = (float4*)d_out;

    // Workspace: asum | asq = 8 KB (same footprint as the verified kernel).
    float* asum = (float*)d_ws;
    float* asq  = asum + NP * NCH;

    void* args[] = { (void*)&x, (void*)&gamma, (void*)&beta, (void*)&perm,
                     (void*)&out, (void*)&asum, (void*)&asq };
    hipLaunchCooperativeKernel((void*)k_fused, dim3(NBLK), dim3(256),
                               args, 0, stream);
}

// Round 5
// 529.397 us; speedup vs baseline: 1.4841x; 1.4841x over previous
//
#include <hip/hip_runtime.h>

#define EPS 0.001f
#define HW_POS 1024          // 32*32 spatial positions per image
#define NCH 256              // channels
#define NCG 64               // channel groups of 4 (float4)
#define NB 256               // batch
#define NP 4                 // partitions
#define SPLIT 8              // blocks per image (was 4; 2048 blocks = 8/CU)
#define POS_PER_BLOCK (HW_POS / SPLIT)   // 128 positions per block
#define N_PER_PC 65536.0f    // PS * HW_POS elements per (partition, channel)

typedef float f32x4 __attribute__((ext_vector_type(4)));

// ---------------- Kernel 0: zero the 8 KB accumulator region -----------------
// Workspace footprint is EXACTLY 8 KB (asum | asq); sc/sh are computed IN
// PLACE over asum/asq by k_finalize.
__global__ __launch_bounds__(256) void k_zero(float* __restrict__ acc) {
    const int i = threadIdx.x;
    #pragma unroll
    for (int k = 0; k < 8; ++k) acc[k * 256 + i] = 0.f;
}

// ---------------- Kernel 1: per-(partition,channel) sums via atomics ---------
// grid = NB*SPLIT = 2048 blocks (8/CU, 32 waves/CU — full occupancy for
// latency hiding), 256 threads. Thread t: cg = t&63 (float4 channel group),
// srow = t>>6 = spatial phase. Wave-load = 64 consecutive float4 = 1 KiB,
// perfectly coalesced. Reads are REGULAR (not nt) on purpose: they populate
// L3 so k_norm's re-read hits the Infinity Cache (x = 256 MiB = L3 size).
__global__ __launch_bounds__(256) void k_partial(const float4* __restrict__ x,
                                                 const int* __restrict__ perm,
                                                 float* __restrict__ asum,
                                                 float* __restrict__ asq) {
    const int slot  = blockIdx.x;            // j*SPLIT + chunk
    const int j     = slot >> 3;             // shuffled image index
    const int chunk = slot & (SPLIT - 1);
    const int b     = perm[j];
    const int p     = j >> 6;                // partition
    const int t     = threadIdx.x;
    const int cg    = t & 63;
    const int srow  = t >> 6;

    const float4* xb = x + (size_t)b * (HW_POS * NCG);
    const int s0 = chunk * POS_PER_BLOCK;

    float4 s = make_float4(0.f, 0.f, 0.f, 0.f);
    float4 q = make_float4(0.f, 0.f, 0.f, 0.f);
    #pragma unroll 8
    for (int si = s0 + srow; si < s0 + POS_PER_BLOCK; si += 4) {
        float4 v = xb[(size_t)si * NCG + cg];
        s.x += v.x; s.y += v.y; s.z += v.z; s.w += v.w;
        q.x += v.x * v.x; q.y += v.y * v.y; q.z += v.z * v.z; q.w += v.w * v.w;
    }

    __shared__ float4 ls[4][64];
    __shared__ float4 lq[4][64];
    ls[srow][cg] = s;
    lq[srow][cg] = q;
    __syncthreads();

    if (srow == 0) {
        float4 a0 = ls[0][cg], a1 = ls[1][cg], a2 = ls[2][cg], a3 = ls[3][cg];
        float4 b0 = lq[0][cg], b1 = lq[1][cg], b2 = lq[2][cg], b3 = lq[3][cg];
        float ts[4] = { a0.x + a1.x + a2.x + a3.x,
                        a0.y + a1.y + a2.y + a3.y,
                        a0.z + a1.z + a2.z + a3.z,
                        a0.w + a1.w + a2.w + a3.w };
        float tq[4] = { b0.x + b1.x + b2.x + b3.x,
                        b0.y + b1.y + b2.y + b3.y,
                        b0.z + b1.z + b2.z + b3.z,
                        b0.w + b1.w + b2.w + b3.w };
        float* sp = asum + p * NCH + cg * 4;
        float* qp = asq  + p * NCH + cg * 4;
        #pragma unroll
        for (int k = 0; k < 4; ++k) {
            atomicAdd(sp + k, ts[k]);
            atomicAdd(qp + k, tq[k]);
        }
    }
}

// ---------------- Kernel 2: finalize fused affine coefficients IN PLACE ------
// One tiny block: asum[idx] <- sc = gamma*rsqrt(var+eps),
//                 asq [idx] <- sh = beta - mean*sc.
// Each thread touches only its own idx — race-free, workspace stays 8 KB.
__global__ __launch_bounds__(256) void k_finalize(float* __restrict__ asum,
                                                  float* __restrict__ asq,
                                                  const float* __restrict__ gamma,
                                                  const float* __restrict__ beta) {
    const int i = threadIdx.x;
    #pragma unroll
    for (int k = 0; k < 4; ++k) {
        const int idx = k * 256 + i;          // idx = p*NCH + c, 0..1023
        const float s    = asum[idx];
        const float q    = asq [idx];
        const float mean = s * (1.0f / N_PER_PC);
        const float var  = q * (1.0f / N_PER_PC) - mean * mean;
        const float inv  = rsqrtf(var + EPS);
        const float scv  = gamma[idx] * inv;
        asum[idx] = scv;                      // sc
        asq [idx] = beta[idx] - mean * scv;   // sh
    }
}

// ---------------- Kernel 3: normalize (non-temporal streaming) ---------------
// Blocks walk in REVERSE order vs k_partial so the L3-resident tail of x is
// re-read first. x loads and out stores are NON-TEMPORAL:
//  - out is never re-read -> nt stores keep it from evicting x out of L3.
//  - each x line is dead after this read -> evict-first.
// Round-4 counter evidence: FETCH_SIZE ~= 1x x total -> pass-2 reads are
// fully L3-absorbed with this scheme. Traffic is at the 512 MB floor.
__global__ __launch_bounds__(256) void k_norm(const float4* __restrict__ x,
                                              const float4* __restrict__ sc4,
                                              const float4* __restrict__ sh4,
                                              const int* __restrict__ perm,
                                              float4* __restrict__ out) {
    const int blk   = (int)gridDim.x - 1 - (int)blockIdx.x;   // reverse order
    const int j     = blk >> 3;
    const int chunk = blk & (SPLIT - 1);
    const int b     = perm[j];
    const int p     = j >> 6;
    const int t     = threadIdx.x;
    const int cg    = t & 63;
    const int srow  = t >> 6;

    // Fused affine coefficients: two coalesced 16B loads (L2 hits).
    const float4 sc = sc4[p * NCG + cg];
    const float4 sh = sh4[p * NCG + cg];

    const float4* xb = x   + (size_t)b * (HW_POS * NCG);
    float4*       ob = out + (size_t)b * (HW_POS * NCG);
    const int s0 = chunk * POS_PER_BLOCK;

    #pragma unroll 8
    for (int si = s0 + srow; si < s0 + POS_PER_BLOCK; si += 4) {
        const size_t idx = (size_t)si * NCG + cg;
        f32x4 v = __builtin_nontemporal_load((const f32x4*)(xb + idx));
        f32x4 r;
        r.x = v.x * sc.x + sh.x;
        r.y = v.y * sc.y + sh.y;
        r.z = v.z * sc.z + sh.z;
        r.w = v.w * sc.w + sh.w;
        __builtin_nontemporal_store(r, (f32x4*)(ob + idx));
    }
}

extern "C" void kernel_launch(void* const* d_in, const int* in_sizes, int n_in,
                              void* d_out, int out_size, void* d_ws, size_t ws_size,
                              hipStream_t stream) {
    const float* x     = (const float*)d_in[0];
    const float* gamma = (const float*)d_in[1];
    const float* beta  = (const float*)d_in[2];
    const int*   perm  = (const int*)d_in[3];
    float* out = (float*)d_out;

    // Workspace: asum | asq = 8 KB (sc/sh live in-place in asum/asq).
    float* asum = (float*)d_ws;
    float* asq  = asum + NP * NCH;

    k_zero<<<1, 256, 0, stream>>>(asum);
    k_partial<<<NB * SPLIT, 256, 0, stream>>>((const float4*)x, perm, asum, asq);
    k_finalize<<<1, 256, 0, stream>>>(asum, asq, gamma, beta);
    k_norm<<<NB * SPLIT, 256, 0, stream>>>((const float4*)x, (const float4*)asum,
                                           (const float4*)asq, perm, (float4*)out);
}

// Round 6
// 493.146 us; speedup vs baseline: 1.5932x; 1.0735x over previous
//
#include <hip/hip_runtime.h>

#define EPS 0.001f
#define HW_POS 1024          // 32*32 spatial positions per image
#define NCH 256              // channels
#define NCG 64               // channel groups of 4 (float4)
#define NB 256               // batch
#define NP 4                 // partitions
#define SPLIT 4              // blocks per image (R5 showed 8 regresses)
#define POS_PER_BLOCK (HW_POS / SPLIT)   // 256 positions per block
#define N_PER_PC 65536.0f    // PS * HW_POS elements per (partition, channel)
#define NSLOT (NB * SPLIT)   // 1024 partial slots

typedef float f32x4 __attribute__((ext_vector_type(4)));

// ---------------- Kernel 1: per-(partition,channel) partial sums -------------
// grid = NB*SPLIT = 1024 blocks, 256 threads. Thread t: cg = t&63 (float4
// channel group), srow = t>>6 = spatial phase. Wave-load = 64 consecutive
// float4 = 1 KiB, perfectly coalesced. Reads are REGULAR (not nt) on purpose:
// they populate L3 so k_norm's re-read hits Infinity Cache (x = 256 MiB = L3).
// Tail: NO atomics — wave 0 stores this block's 256-channel partials to a
// private slab slot (psum/psq, 1 MB each). Every slot is fully written, so no
// pre-zero kernel is needed (ws is harness-poisoned each iteration; we never
// read uninitialized ws).
__global__ __launch_bounds__(256) void k_partial(const float4* __restrict__ x,
                                                 const int* __restrict__ perm,
                                                 float4* __restrict__ psum4,
                                                 float4* __restrict__ psq4) {
    const int slot  = blockIdx.x;            // j*SPLIT + chunk
    const int j     = slot >> 2;             // shuffled image index
    const int chunk = slot & (SPLIT - 1);
    const int b     = perm[j];
    const int t     = threadIdx.x;
    const int cg    = t & 63;
    const int srow  = t >> 6;

    const float4* xb = x + (size_t)b * (HW_POS * NCG);
    const int s0 = chunk * POS_PER_BLOCK;

    float4 s = make_float4(0.f, 0.f, 0.f, 0.f);
    float4 q = make_float4(0.f, 0.f, 0.f, 0.f);
    #pragma unroll 8
    for (int si = s0 + srow; si < s0 + POS_PER_BLOCK; si += 4) {
        float4 v = xb[(size_t)si * NCG + cg];
        s.x += v.x; s.y += v.y; s.z += v.z; s.w += v.w;
        q.x += v.x * v.x; q.y += v.y * v.y; q.z += v.z * v.z; q.w += v.w * v.w;
    }

    __shared__ float4 ls[4][64];
    __shared__ float4 lq[4][64];
    ls[srow][cg] = s;
    lq[srow][cg] = q;
    __syncthreads();

    if (srow == 0) {
        float4 a0 = ls[0][cg], a1 = ls[1][cg], a2 = ls[2][cg], a3 = ls[3][cg];
        float4 b0 = lq[0][cg], b1 = lq[1][cg], b2 = lq[2][cg], b3 = lq[3][cg];
        float4 ts = make_float4(a0.x + a1.x + a2.x + a3.x,
                                a0.y + a1.y + a2.y + a3.y,
                                a0.z + a1.z + a2.z + a3.z,
                                a0.w + a1.w + a2.w + a3.w);
        float4 tq = make_float4(b0.x + b1.x + b2.x + b3.x,
                                b0.y + b1.y + b2.y + b3.y,
                                b0.z + b1.z + b2.z + b3.z,
                                b0.w + b1.w + b2.w + b3.w);
        // Coalesced 1 KB wave-store, zero contention.
        psum4[(size_t)slot * NCG + cg] = ts;
        psq4 [(size_t)slot * NCG + cg] = tq;
    }
}

// ---------------- Kernel 2: deterministic reduce + fused coefficients --------
// 4 blocks (one per partition) x 256 threads (one per channel). Partition p's
// slots are exactly [p*256, (p+1)*256) since slot = j*SPLIT+chunk and
// p = j>>6. Thread (p,c) sums 256 partials; threads read consecutive c ->
// fully coalesced, 2 MB total, L2/L3-resident (just written). Emits
// sc = gamma*rsqrt(var+eps), sh = beta - mean*sc.
__global__ __launch_bounds__(256) void k_reduce(const float* __restrict__ psum,
                                                const float* __restrict__ psq,
                                                const float* __restrict__ gamma,
                                                const float* __restrict__ beta,
                                                float* __restrict__ sc,
                                                float* __restrict__ sh) {
    const int p = blockIdx.x;      // 0..3
    const int c = threadIdx.x;     // 0..255
    const int base = p * 256;      // first slot of this partition

    float s = 0.f, q = 0.f;
    #pragma unroll 8
    for (int k = 0; k < 256; ++k) {
        s += psum[(size_t)(base + k) * NCH + c];
        q += psq [(size_t)(base + k) * NCH + c];
    }
    const float mean = s * (1.0f / N_PER_PC);
    const float var  = q * (1.0f / N_PER_PC) - mean * mean;
    const float inv  = rsqrtf(var + EPS);
    const float scv  = gamma[p * NCH + c] * inv;
    sc[p * NCH + c] = scv;
    sh[p * NCH + c] = beta[p * NCH + c] - mean * scv;
}

// ---------------- Kernel 3: normalize (non-temporal streaming) ---------------
// Blocks walk in REVERSE order vs k_partial so the L3-resident tail of x is
// re-read first. x loads and out stores are NON-TEMPORAL:
//  - out is never re-read -> nt stores keep it from evicting x out of L3.
//  - each x line is dead after this read -> evict-first.
// R4 counter evidence: total FETCH ~= 1x x -> pass-2 reads fully L3-absorbed.
__global__ __launch_bounds__(256) void k_norm(const float4* __restrict__ x,
                                              const float4* __restrict__ sc4,
                                              const float4* __restrict__ sh4,
                                              const int* __restrict__ perm,
                                              float4* __restrict__ out) {
    const int blk   = (int)gridDim.x - 1 - (int)blockIdx.x;   // reverse order
    const int j     = blk >> 2;
    const int chunk = blk & (SPLIT - 1);
    const int b     = perm[j];
    const int p     = j >> 6;
    const int t     = threadIdx.x;
    const int cg    = t & 63;
    const int srow  = t >> 6;

    // Fused affine coefficients: two coalesced 16B loads (L2 hits).
    const float4 sc = sc4[p * NCG + cg];
    const float4 sh = sh4[p * NCG + cg];

    const float4* xb = x   + (size_t)b * (HW_POS * NCG);
    float4*       ob = out + (size_t)b * (HW_POS * NCG);
    const int s0 = chunk * POS_PER_BLOCK;

    #pragma unroll 8
    for (int si = s0 + srow; si < s0 + POS_PER_BLOCK; si += 4) {
        const size_t idx = (size_t)si * NCG + cg;
        f32x4 v = __builtin_nontemporal_load((const f32x4*)(xb + idx));
        f32x4 r;
        r.x = v.x * sc.x + sh.x;
        r.y = v.y * sc.y + sh.y;
        r.z = v.z * sc.z + sh.z;
        r.w = v.w * sc.w + sh.w;
        __builtin_nontemporal_store(r, (f32x4*)(ob + idx));
    }
}

extern "C" void kernel_launch(void* const* d_in, const int* in_sizes, int n_in,
                              void* d_out, int out_size, void* d_ws, size_t ws_size,
                              hipStream_t stream) {
    const float* x     = (const float*)d_in[0];
    const float* gamma = (const float*)d_in[1];
    const float* beta  = (const float*)d_in[2];
    const int*   perm  = (const int*)d_in[3];
    float* out = (float*)d_out;

    // Workspace layout (ws >= 1 GiB per the harness's 1 GiB poison fill):
    //   psum [1 MB] | psq [1 MB] | sc [4 KB] | sh [4 KB]
    float* psum = (float*)d_ws;
    float* psq  = psum + (size_t)NSLOT * NCH;
    float* sc   = psq  + (size_t)NSLOT * NCH;
    float* sh   = sc   + NP * NCH;

    k_partial<<<NB * SPLIT, 256, 0, stream>>>((const float4*)x, perm,
                                              (float4*)psum, (float4*)psq);
    k_reduce<<<NP, 256, 0, stream>>>(psum, psq, gamma, beta, sc, sh);
    k_norm<<<NB * SPLIT, 256, 0, stream>>>((const float4*)x, (const float4*)sc,
                                           (const float4*)sh, perm, (float4*)out);
}